// Round 2
// baseline (142.126 us; speedup 1.0000x reference)
//
#include <hip/hip_runtime.h>

namespace {
constexpr int kNE = 14;
constexpr int kNC = 20;
constexpr int kCloner = 13;
constexpr int kCA = 17;   // NE + 3
constexpr int kB = 32;
constexpr int kH = 256;
constexpr int kW = 256;

constexpr int kT = 32;        // core tile (spatial)
constexpr int kE = kT + 4;    // extended tile with halo 2 (labels need halo 2)
constexpr int kThreads = 256;
}

// Packed stage-1 state (uint16):
//   bits 0..3 : label (argmax of ch 0..13)
//   bit  4    : cloner (ch13 > 0.5)
//   bit  5    : empty  (ch0  > 0.5)
//   bits 8..11: ca_init (int of ch17, 0..13)
//
// CA state (uint16):
//   bit  0    : empty
//   bit  1    : active (= cloner && ca!=0 && ca!=13)
//   bits 4..7 : fca (original final-CA value of this pixel; the vec source value — never changes)
//   bits 8..11: src  (fca of the neighbor that last overwrote this pixel)
//   bit  12   : overwritten flag

__global__ __launch_bounds__(kThreads)
void bc_fused(const float* __restrict__ world,
              const float* __restrict__ ev,
              const float* __restrict__ info,
              float* __restrict__ out)
{
    __shared__ unsigned short sPack[kE][kE];
    __shared__ unsigned short sA[kE][kE];
    __shared__ unsigned short sB[kE][kE];
    __shared__ float sEV[kNE * kNC];
    __shared__ unsigned short sVbits[kNE];

    const int tid = threadIdx.x;
    const int b  = blockIdx.z;
    const int h0 = blockIdx.y * kT;
    const int w0 = blockIdx.x * kT;
    const size_t plane = (size_t)kH * kW;
    const float* wb = world + (size_t)b * kNC * plane;
    float*       ob = out   + (size_t)b * kNC * plane;

    // elem_vecs into LDS + per-row state bits (visible after the stage-1 barrier)
    for (int i = tid; i < kNE * kNC; i += kThreads) sEV[i] = ev[i];   // 280 > 256: must loop!
    if (tid < kNE) {
        const float e0  = ev[tid * kNC + 0];
        const float c13 = ev[tid * kNC + kCloner];
        const float c17 = ev[tid * kNC + kCA];
        unsigned short vb = 0;
        if (e0 > 0.5f) vb |= 1;                                        // empty after overwrite
        if (c13 > 0.5f && c17 != 0.0f && c17 != 13.0f) vb |= 2;        // active after overwrite
        sVbits[tid] = vb;
    }

    // ---- Stage 1: pack label/cloner/empty/ca_init for extended tile (halo 2, torus wrap)
    for (int idx = tid; idx < kE * kE; idx += kThreads) {
        const int eh = idx / kE;
        const int ew = idx - eh * kE;
        const int h = (h0 + eh - 2) & (kH - 1);
        const int w = (w0 + ew - 2) & (kW - 1);
        const size_t off = (size_t)h * kW + w;
        const float c0 = wb[off];
        float best = c0;
        int lab = 0;
        float c13 = 0.0f;
        #pragma unroll
        for (int c = 1; c < kNE; ++c) {
            const float v = wb[(size_t)c * plane + off];
            if (c == kCloner) c13 = v;
            if (v > best) { best = v; lab = c; }   // first-max wins (jnp.argmax)
        }
        const int ca0 = (int)wb[(size_t)kCA * plane + off];   // exact small ints 0..13
        unsigned short p = (unsigned short)(lab | (ca0 << 8));
        if (c13 > 0.5f) p |= 16;
        if (c0  > 0.5f) p |= 32;
        sPack[eh][ew] = p;
    }
    __syncthreads();

    // ---- Stage 2: final CA (phase A) on tile+halo1; init CA state S0
    constexpr int kS0 = kE - 2;  // 34
    for (int idx = tid; idx < kS0 * kS0; idx += kThreads) {
        const int eh = idx / kS0 + 1;
        const int ew = idx % kS0 + 1;
        const unsigned short p = sPack[eh][ew];
        int fca = 0;
        if (p & 16) {                       // cloner: sequentially absorb neighbor labels
            int ca = (p >> 8) & 15;
            if (ca == 0 || ca == 13) ca = sPack[eh + 1][ew] & 15;  // below = roll(-1,h) -> h+1
            if (ca == 0 || ca == 13) ca = sPack[eh - 1][ew] & 15;  // above -> h-1
            if (ca == 0 || ca == 13) ca = sPack[eh][ew - 1] & 15;  // left  -> w-1
            if (ca == 0 || ca == 13) ca = sPack[eh][ew + 1] & 15;  // right -> w+1
            fca = ca;
        }
        unsigned short s = (unsigned short)(fca << 4);
        if (p & 32) s |= 1;                                   // empty
        if ((p & 16) && fca != 0 && fca != 13) s |= 2;        // active
        sA[eh][ew] = s;
    }

    // ---- Stage 3: 4-direction mask evolution (phase B), ping-pong LDS.
    // Regions shrink so every neighbor read stays inside the previous step's region.
    {
        unsigned short (*prev)[kE] = sA;
        unsigned short (*next)[kE] = sB;
        const int dh[4]   = {1, -1, 0, 0};
        const int dw[4]   = {0, 0, -1, 1};
        const int rhlo[4] = {1, 2, 2, 2};
        const int rhhi[4] = {kE - 3, kE - 3, kE - 3, kE - 3};      // 33
        const int rwlo[4] = {1, 1, 2, 2};
        const int rwhi[4] = {kE - 2, kE - 2, kE - 2, kE - 3};      // 34,34,34,33
        for (int d = 0; d < 4; ++d) {
            __syncthreads();
            const int nh = rhhi[d] - rhlo[d] + 1;
            const int nw = rwhi[d] - rwlo[d] + 1;
            for (int idx = tid; idx < nh * nw; idx += kThreads) {
                const int eh = rhlo[d] + idx / nw;
                const int ew = rwlo[d] + idx % nw;
                unsigned short s = prev[eh][ew];
                const unsigned short ns = prev[eh + dh[d]][ew + dw[d]];
                if ((ns & 2) && (s & 1)) {      // neighbor active && self empty
                    const int v = (ns >> 4) & 15;   // neighbor's ORIGINAL fca (vec is fixed)
                    s = (unsigned short)((s & 0x00F0) | sVbits[v] | (v << 8) | 0x1000);
                }
                next[eh][ew] = s;
            }
            unsigned short (*t)[kE] = prev; prev = next; next = t;
        }
        __syncthreads();

        // ---- Stage 4: write output (prev holds final state on the core tile)
        for (int idx = tid; idx < kT * kT; idx += kThreads) {
            const int th = idx / kT;
            const int tw = idx - th * kT;
            const unsigned short s = prev[th + 2][tw + 2];
            const size_t off = (size_t)(h0 + th) * kW + (w0 + tw);
            const bool ovr = (s & 0x1000) != 0;
            const int src  = (s >> 8) & 15;
            const float fcaf = (float)((s >> 4) & 15);
            #pragma unroll
            for (int c = 0; c < kNC; ++c) {
                const float inv = wb[(size_t)c * plane + off];
                float val;
                if (ovr)            val = sEV[src * kNC + c];
                else if (c == kCA)  val = fcaf;
                else                val = inv;
                ob[(size_t)c * plane + off] = val;
            }
        }
    }

    // info passthrough (one block does it)
    if (blockIdx.x == 0 && blockIdx.y == 0 && blockIdx.z == 0 && tid < kB) {
        out[(size_t)kB * kNC * plane + tid] = info[tid];
    }
}

extern "C" void kernel_launch(void* const* d_in, const int* in_sizes, int n_in,
                              void* d_out, int out_size, void* d_ws, size_t ws_size,
                              hipStream_t stream) {
    const float* world = (const float*)d_in[0];
    const float* ev    = (const float*)d_in[1];
    const float* info  = (const float*)d_in[2];
    float* out = (float*)d_out;
    dim3 grid(kW / kT, kH / kT, kB);   // 8 x 8 x 32 = 2048 blocks
    bc_fused<<<grid, kThreads, 0, stream>>>(world, ev, info, out);
}

// Round 3
// 99.035 us; speedup vs baseline: 1.4351x; 1.4351x over previous
//
#include <hip/hip_runtime.h>

namespace {
constexpr int kNE = 14;
constexpr int kNC = 20;
constexpr int kCloner = 13;
constexpr int kCA = 17;   // NE + 3
constexpr int kB = 32;
constexpr int kH = 256;
constexpr int kW = 256;

constexpr int kT = 32;        // core tile (spatial)
constexpr int kE = kT + 4;    // rows of extended tile (halo 2)
constexpr int kLW = 40;       // lds row width: [w0-4, w0+36) in aligned float4 groups
constexpr int kThreads = 256;
}

// sPack (uint16):  bits0..3 label | bit4 cloner(label==13) | bit5 empty(label==0) | bits8..11 ca_init
// CA state (uint16): bit0 empty | bit1 active | bits4..7 fca | bits8..11 src | bit12 overwritten

__global__ __launch_bounds__(kThreads)
void bc_fused(const float* __restrict__ world,
              const float* __restrict__ ev,
              const float* __restrict__ info,
              float* __restrict__ out)
{
    __shared__ unsigned short sPack[kE][kLW];
    __shared__ unsigned short sA[kE][kLW];
    __shared__ unsigned short sB[kE][kLW];
    __shared__ float sEV[kNE * kNC];
    __shared__ unsigned short sVbits[kNE];

    const int tid = threadIdx.x;
    const int b  = blockIdx.z;
    const int h0 = blockIdx.y * kT;
    const int w0 = blockIdx.x * kT;
    const size_t plane = (size_t)kH * kW;
    const float* wb = world + (size_t)b * kNC * plane;
    float*       ob = out   + (size_t)b * kNC * plane;

    for (int i = tid; i < kNE * kNC; i += kThreads) sEV[i] = ev[i];
    if (tid < kNE) {
        const float e0  = ev[tid * kNC + 0];
        const float c13 = ev[tid * kNC + kCloner];
        const float c17 = ev[tid * kNC + kCA];
        unsigned short vb = 0;
        if (e0 > 0.5f) vb |= 1;                                     // empty after overwrite
        if (c13 > 0.5f && c17 != 0.0f && c17 != 13.0f) vb |= 2;     // active after overwrite
        sVbits[tid] = vb;
    }

    // ---- Stage 1: pack label/cloner/empty/ca_init, float4-vectorized.
    // Row = 10 aligned float4 groups covering [w0-4, w0+36); lds col lw = w - (w0-4).
    // Channels 0..13 are an exact one-hot -> label = channel holding 1.0.
    for (int idx = tid; idx < kE * 10; idx += kThreads) {
        const int eh = idx / 10;
        const int k  = idx - eh * 10;
        const int h = (h0 + eh - 2) & (kH - 1);
        const int w = (w0 - 4 + 4 * k) & (kW - 1);   // stays 4-aligned after wrap (256%4==0)
        const size_t off = (size_t)h * kW + w;
        int lab0 = 0, lab1 = 0, lab2 = 0, lab3 = 0;
        #pragma unroll
        for (int c = 0; c < kNE; ++c) {
            const float4 v = *reinterpret_cast<const float4*>(wb + (size_t)c * plane + off);
            if (v.x > 0.5f) lab0 = c;
            if (v.y > 0.5f) lab1 = c;
            if (v.z > 0.5f) lab2 = c;
            if (v.w > 0.5f) lab3 = c;
        }
        const float4 ca4 = *reinterpret_cast<const float4*>(wb + (size_t)kCA * plane + off);
        const int lab[4] = {lab0, lab1, lab2, lab3};
        const int cai[4] = {(int)ca4.x, (int)ca4.y, (int)ca4.z, (int)ca4.w};
        #pragma unroll
        for (int j = 0; j < 4; ++j) {
            unsigned short p = (unsigned short)(lab[j] | (cai[j] << 8));
            if (lab[j] == kCloner) p |= 16;
            if (lab[j] == 0)       p |= 32;
            sPack[eh][4 * k + j] = p;
        }
    }
    __syncthreads();

    // ---- Stage 2: final CA on tile+halo1 (rows 1..34, lw 3..36); init CA state.
    for (int idx = tid; idx < 34 * 34; idx += kThreads) {
        const int eh = idx / 34 + 1;
        const int lw = idx % 34 + 3;
        const unsigned short p = sPack[eh][lw];
        int fca = 0;
        if (p & 16) {
            int ca = (p >> 8) & 15;
            if (ca == 0 || ca == 13) ca = sPack[eh + 1][lw] & 15;  // below
            if (ca == 0 || ca == 13) ca = sPack[eh - 1][lw] & 15;  // above
            if (ca == 0 || ca == 13) ca = sPack[eh][lw - 1] & 15;  // left
            if (ca == 0 || ca == 13) ca = sPack[eh][lw + 1] & 15;  // right
            fca = ca;
        }
        unsigned short s = (unsigned short)(fca << 4);
        if (p & 32) s |= 1;
        if ((p & 16) && fca != 0 && fca != 13) s |= 2;
        sA[eh][lw] = s;
    }

    // ---- Stage 3: 4-direction mask evolution, ping-pong LDS (shrinking valid regions).
    unsigned short (*prev)[kLW] = sA;
    unsigned short (*next)[kLW] = sB;
    {
        const int dh[4]   = {1, -1, 0, 0};
        const int dw[4]   = {0, 0, -1, 1};
        const int rhlo[4] = {1, 2, 2, 2};
        const int rhhi[4] = {33, 33, 33, 33};
        const int rwlo[4] = {3, 3, 4, 4};
        const int rwhi[4] = {36, 36, 36, 35};
        for (int d = 0; d < 4; ++d) {
            __syncthreads();
            const int nh = rhhi[d] - rhlo[d] + 1;
            const int nw = rwhi[d] - rwlo[d] + 1;
            for (int idx = tid; idx < nh * nw; idx += kThreads) {
                const int eh = rhlo[d] + idx / nw;
                const int lw = rwlo[d] + idx % nw;
                unsigned short s = prev[eh][lw];
                const unsigned short ns = prev[eh + dh[d]][lw + dw[d]];
                if ((ns & 2) && (s & 1)) {
                    const int v = (ns >> 4) & 15;   // neighbor's ORIGINAL fca (vec frozen)
                    s = (unsigned short)((s & 0x00F0) | sVbits[v] | (v << 8) | 0x1000);
                }
                next[eh][lw] = s;
            }
            unsigned short (*t)[kLW] = prev; prev = next; next = t;
        }
    }
    __syncthreads();

    // ---- Stage 4: write all 20 channels, float4-vectorized; read only ch 14,15,16,18,19.
    // ch 0..13 non-overwritten = exact one-hot(label); ch17 non-overwritten = fca.
    {
        const int g  = tid;           // 256 groups: 32 rows x 8 float4-groups
        const int th = g >> 3;
        const int tw = (g & 7) * 4;
        const int eh = th + 2;
        const size_t off = (size_t)(h0 + th) * kW + (w0 + tw);

        bool  o[4]; int src[4]; float fcaf[4]; int lb[4];
        #pragma unroll
        for (int j = 0; j < 4; ++j) {
            const unsigned short s = prev[eh][tw + 4 + j];
            o[j]    = (s & 0x1000) != 0;
            src[j]  = (s >> 8) & 15;
            fcaf[j] = (float)((s >> 4) & 15);
            lb[j]   = sPack[eh][tw + 4 + j] & 15;
        }

        #pragma unroll
        for (int c = 0; c < kNC; ++c) {
            float base[4];
            if (c >= kNE && c != kCA) {
                const float4 v = *reinterpret_cast<const float4*>(wb + (size_t)c * plane + off);
                base[0] = v.x; base[1] = v.y; base[2] = v.z; base[3] = v.w;
            } else if (c == kCA) {
                base[0] = fcaf[0]; base[1] = fcaf[1]; base[2] = fcaf[2]; base[3] = fcaf[3];
            } else {
                #pragma unroll
                for (int j = 0; j < 4; ++j) base[j] = (lb[j] == c) ? 1.0f : 0.0f;
            }
            float4 r;
            r.x = o[0] ? sEV[src[0] * kNC + c] : base[0];
            r.y = o[1] ? sEV[src[1] * kNC + c] : base[1];
            r.z = o[2] ? sEV[src[2] * kNC + c] : base[2];
            r.w = o[3] ? sEV[src[3] * kNC + c] : base[3];
            *reinterpret_cast<float4*>(ob + (size_t)c * plane + off) = r;
        }
    }

    if (blockIdx.x == 0 && blockIdx.y == 0 && blockIdx.z == 0 && tid < kB) {
        out[(size_t)kB * kNC * plane + tid] = info[tid];
    }
}

extern "C" void kernel_launch(void* const* d_in, const int* in_sizes, int n_in,
                              void* d_out, int out_size, void* d_ws, size_t ws_size,
                              hipStream_t stream) {
    const float* world = (const float*)d_in[0];
    const float* ev    = (const float*)d_in[1];
    const float* info  = (const float*)d_in[2];
    float* out = (float*)d_out;
    dim3 grid(kW / kT, kH / kT, kB);   // 8 x 8 x 32 = 2048 blocks
    bc_fused<<<grid, kThreads, 0, stream>>>(world, ev, info, out);
}

// Round 4
// 72.486 us; speedup vs baseline: 1.9607x; 1.3663x over previous
//
#include <hip/hip_runtime.h>

namespace {
constexpr int kNE = 14;
constexpr int kNC = 20;
constexpr int kCloner = 13;
constexpr int kCA = 17;   // NE + 3
constexpr int kB = 32;
constexpr int kH = 256;
constexpr int kW = 256;

constexpr int kT = 32;        // core tile
constexpr int kE = kT + 4;    // extended rows (halo 2)
constexpr int kLW = 40;       // lds row width: [w0-4, w0+36)
constexpr int kThreads = 256;
constexpr size_t kPlane = (size_t)kH * kW;
}

// pack (uint16): bits0..3 label | bit4 cloner(label==13) | bit5 empty(label==0) | bits8..11 ca_init
// CA state (uint16): bit0 empty | bit1 active | bits4..7 fca | bits8..11 src | bit12 overwritten

// ---------------- K1: per-pixel pack, pure streaming ----------------
__global__ __launch_bounds__(kThreads)
void k_pack(const float* __restrict__ world, const float* __restrict__ info,
            float* __restrict__ out, unsigned short* __restrict__ pack)
{
    const int g = blockIdx.x * kThreads + threadIdx.x;   // 524288 float4-groups total
    const int b = g >> 14;                                // 16384 groups per plane
    const int rem = g & 16383;
    const size_t off = (size_t)rem << 2;
    const float* wb = world + (size_t)b * kNC * kPlane;

    int lab[4] = {0, 0, 0, 0};
    #pragma unroll
    for (int c = 0; c < kNE; ++c) {
        const float4 v = *reinterpret_cast<const float4*>(wb + (size_t)c * kPlane + off);
        if (v.x > 0.5f) lab[0] = c;      // exact one-hot: unique channel holds 1.0
        if (v.y > 0.5f) lab[1] = c;
        if (v.z > 0.5f) lab[2] = c;
        if (v.w > 0.5f) lab[3] = c;
    }
    const float4 ca4 = *reinterpret_cast<const float4*>(wb + (size_t)kCA * kPlane + off);
    const int cai[4] = {(int)ca4.x, (int)ca4.y, (int)ca4.z, (int)ca4.w};
    unsigned short p[4];
    #pragma unroll
    for (int j = 0; j < 4; ++j) {
        unsigned short q = (unsigned short)(lab[j] | (cai[j] << 8));
        if (lab[j] == kCloner) q |= 16;
        if (lab[j] == 0)       q |= 32;
        p[j] = q;
    }
    ushort4 st; st.x = p[0]; st.y = p[1]; st.z = p[2]; st.w = p[3];
    *reinterpret_cast<ushort4*>(pack + (size_t)b * kPlane + off) = st;

    if (g < kB) out[(size_t)kB * kNC * kPlane + g] = info[g];   // info passthrough
}

// ---------------- K2: CA evolution + output, tiled ----------------
__global__ __launch_bounds__(kThreads)
void k_apply(const float* __restrict__ world, const float* __restrict__ ev,
             const unsigned short* __restrict__ pack, float* __restrict__ out)
{
    __shared__ unsigned short sPack[kE][kLW];
    __shared__ unsigned short sA[kE][kLW];
    __shared__ unsigned short sB[kE][kLW];
    __shared__ float sEV[kNE * kNC];
    __shared__ unsigned short sVbits[kNE];

    const int tid = threadIdx.x;
    const int b  = blockIdx.z;
    const int h0 = blockIdx.y * kT;
    const int w0 = blockIdx.x * kT;
    const float* wb = world + (size_t)b * kNC * kPlane;
    float*       ob = out   + (size_t)b * kNC * kPlane;
    const unsigned short* pb = pack + (size_t)b * kPlane;

    // Early-issue the 5 pass-through channel loads (latency hides under LDS phases).
    const int th  = tid >> 3;
    const int tw4 = (tid & 7) * 4;
    const size_t off4 = (size_t)(h0 + th) * kW + (w0 + tw4);
    float4 extra[5];
    extra[0] = *reinterpret_cast<const float4*>(wb + (size_t)14 * kPlane + off4);
    extra[1] = *reinterpret_cast<const float4*>(wb + (size_t)15 * kPlane + off4);
    extra[2] = *reinterpret_cast<const float4*>(wb + (size_t)16 * kPlane + off4);
    extra[3] = *reinterpret_cast<const float4*>(wb + (size_t)18 * kPlane + off4);
    extra[4] = *reinterpret_cast<const float4*>(wb + (size_t)19 * kPlane + off4);

    for (int i = tid; i < kNE * kNC; i += kThreads) sEV[i] = ev[i];
    if (tid < kNE) {
        const float e0  = ev[tid * kNC + 0];
        const float c13 = ev[tid * kNC + kCloner];
        const float c17 = ev[tid * kNC + kCA];
        unsigned short vb = 0;
        if (e0 > 0.5f) vb |= 1;                                     // empty after overwrite
        if (c13 > 0.5f && c17 != 0.0f && c17 != 13.0f) vb |= 2;     // active after overwrite
        sVbits[tid] = vb;
    }

    // Stage 1': packed extended tile from global (ushort4, aligned; wrap keeps 4-alignment).
    for (int idx = tid; idx < kE * 10; idx += kThreads) {
        const int eh = idx / 10;
        const int k  = idx - eh * 10;
        const int h = (h0 + eh - 2) & (kH - 1);
        const int w = (w0 - 4 + 4 * k) & (kW - 1);
        const ushort4 v = *reinterpret_cast<const ushort4*>(pb + (size_t)h * kW + w);
        sPack[eh][4 * k + 0] = v.x;
        sPack[eh][4 * k + 1] = v.y;
        sPack[eh][4 * k + 2] = v.z;
        sPack[eh][4 * k + 3] = v.w;
    }
    __syncthreads();

    // Stage 2: final CA on tile+halo1 (rows 1..34, lw 3..36); init CA state.
    for (int idx = tid; idx < 34 * 34; idx += kThreads) {
        const int eh = idx / 34 + 1;
        const int lw = idx % 34 + 3;
        const unsigned short p = sPack[eh][lw];
        int fca = 0;
        if (p & 16) {
            int ca = (p >> 8) & 15;
            if (ca == 0 || ca == 13) ca = sPack[eh + 1][lw] & 15;  // below
            if (ca == 0 || ca == 13) ca = sPack[eh - 1][lw] & 15;  // above
            if (ca == 0 || ca == 13) ca = sPack[eh][lw - 1] & 15;  // left
            if (ca == 0 || ca == 13) ca = sPack[eh][lw + 1] & 15;  // right
            fca = ca;
        }
        unsigned short s = (unsigned short)(fca << 4);
        if (p & 32) s |= 1;
        if ((p & 16) && fca != 0 && fca != 13) s |= 2;
        sA[eh][lw] = s;
    }

    // Stage 3: 4-direction mask evolution, ping-pong LDS (shrinking regions).
    unsigned short (*prev)[kLW] = sA;
    unsigned short (*next)[kLW] = sB;
    {
        const int dh[4]   = {1, -1, 0, 0};
        const int dw[4]   = {0, 0, -1, 1};
        const int rhlo[4] = {1, 2, 2, 2};
        const int rhhi[4] = {33, 33, 33, 33};
        const int rwlo[4] = {3, 3, 4, 4};
        const int rwhi[4] = {36, 36, 36, 35};
        for (int d = 0; d < 4; ++d) {
            __syncthreads();
            const int nh = rhhi[d] - rhlo[d] + 1;
            const int nw = rwhi[d] - rwlo[d] + 1;
            for (int idx = tid; idx < nh * nw; idx += kThreads) {
                const int eh = rhlo[d] + idx / nw;
                const int lw = rwlo[d] + idx % nw;
                unsigned short s = prev[eh][lw];
                const unsigned short ns = prev[eh + dh[d]][lw + dw[d]];
                if ((ns & 2) && (s & 1)) {
                    const int v = (ns >> 4) & 15;   // neighbor's ORIGINAL fca (vec frozen)
                    s = (unsigned short)((s & 0x00F0) | sVbits[v] | (v << 8) | 0x1000);
                }
                next[eh][lw] = s;
            }
            unsigned short (*t)[kLW] = prev; prev = next; next = t;
        }
    }
    __syncthreads();

    // Stage 4: write all 20 channels (float4). ch0..13 = one-hot(label) or vec;
    // ch17 = fca or vec; ch14,15,16,18,19 = register passthrough or vec.
    {
        const int eh = th + 2;
        bool  o[4]; int src[4]; float fcaf[4]; int lb[4];
        #pragma unroll
        for (int j = 0; j < 4; ++j) {
            const unsigned short s = prev[eh][tw4 + 4 + j];
            o[j]    = (s & 0x1000) != 0;
            src[j]  = (s >> 8) & 15;
            fcaf[j] = (float)((s >> 4) & 15);
            lb[j]   = sPack[eh][tw4 + 4 + j] & 15;
        }
        #pragma unroll
        for (int c = 0; c < kNC; ++c) {
            float base[4];
            if (c < kNE) {
                #pragma unroll
                for (int j = 0; j < 4; ++j) base[j] = (lb[j] == c) ? 1.0f : 0.0f;
            } else if (c == kCA) {
                #pragma unroll
                for (int j = 0; j < 4; ++j) base[j] = fcaf[j];
            } else {
                const float4 v = extra[c < kCA ? c - kNE : c - kNE - 1];  // const idx when unrolled
                base[0] = v.x; base[1] = v.y; base[2] = v.z; base[3] = v.w;
            }
            float4 r;
            r.x = o[0] ? sEV[src[0] * kNC + c] : base[0];
            r.y = o[1] ? sEV[src[1] * kNC + c] : base[1];
            r.z = o[2] ? sEV[src[2] * kNC + c] : base[2];
            r.w = o[3] ? sEV[src[3] * kNC + c] : base[3];
            *reinterpret_cast<float4*>(ob + (size_t)c * kPlane + off4) = r;
        }
    }
}

// ---------------- Fallback: round-3 fused kernel (used only if ws too small) ----------------
__global__ __launch_bounds__(kThreads)
void bc_fused(const float* __restrict__ world, const float* __restrict__ ev,
              const float* __restrict__ info, float* __restrict__ out)
{
    __shared__ unsigned short sPack[kE][kLW];
    __shared__ unsigned short sA[kE][kLW];
    __shared__ unsigned short sB[kE][kLW];
    __shared__ float sEV[kNE * kNC];
    __shared__ unsigned short sVbits[kNE];

    const int tid = threadIdx.x;
    const int b  = blockIdx.z;
    const int h0 = blockIdx.y * kT;
    const int w0 = blockIdx.x * kT;
    const float* wb = world + (size_t)b * kNC * kPlane;
    float*       ob = out   + (size_t)b * kNC * kPlane;

    for (int i = tid; i < kNE * kNC; i += kThreads) sEV[i] = ev[i];
    if (tid < kNE) {
        const float e0  = ev[tid * kNC + 0];
        const float c13 = ev[tid * kNC + kCloner];
        const float c17 = ev[tid * kNC + kCA];
        unsigned short vb = 0;
        if (e0 > 0.5f) vb |= 1;
        if (c13 > 0.5f && c17 != 0.0f && c17 != 13.0f) vb |= 2;
        sVbits[tid] = vb;
    }
    for (int idx = tid; idx < kE * 10; idx += kThreads) {
        const int eh = idx / 10;
        const int k  = idx - eh * 10;
        const int h = (h0 + eh - 2) & (kH - 1);
        const int w = (w0 - 4 + 4 * k) & (kW - 1);
        const size_t off = (size_t)h * kW + w;
        int lab[4] = {0,0,0,0};
        #pragma unroll
        for (int c = 0; c < kNE; ++c) {
            const float4 v = *reinterpret_cast<const float4*>(wb + (size_t)c * kPlane + off);
            if (v.x > 0.5f) lab[0] = c;
            if (v.y > 0.5f) lab[1] = c;
            if (v.z > 0.5f) lab[2] = c;
            if (v.w > 0.5f) lab[3] = c;
        }
        const float4 ca4 = *reinterpret_cast<const float4*>(wb + (size_t)kCA * kPlane + off);
        const int cai[4] = {(int)ca4.x, (int)ca4.y, (int)ca4.z, (int)ca4.w};
        #pragma unroll
        for (int j = 0; j < 4; ++j) {
            unsigned short p = (unsigned short)(lab[j] | (cai[j] << 8));
            if (lab[j] == kCloner) p |= 16;
            if (lab[j] == 0)       p |= 32;
            sPack[eh][4 * k + j] = p;
        }
    }
    __syncthreads();
    for (int idx = tid; idx < 34 * 34; idx += kThreads) {
        const int eh = idx / 34 + 1;
        const int lw = idx % 34 + 3;
        const unsigned short p = sPack[eh][lw];
        int fca = 0;
        if (p & 16) {
            int ca = (p >> 8) & 15;
            if (ca == 0 || ca == 13) ca = sPack[eh + 1][lw] & 15;
            if (ca == 0 || ca == 13) ca = sPack[eh - 1][lw] & 15;
            if (ca == 0 || ca == 13) ca = sPack[eh][lw - 1] & 15;
            if (ca == 0 || ca == 13) ca = sPack[eh][lw + 1] & 15;
            fca = ca;
        }
        unsigned short s = (unsigned short)(fca << 4);
        if (p & 32) s |= 1;
        if ((p & 16) && fca != 0 && fca != 13) s |= 2;
        sA[eh][lw] = s;
    }
    unsigned short (*prev)[kLW] = sA;
    unsigned short (*next)[kLW] = sB;
    {
        const int dh[4]   = {1, -1, 0, 0};
        const int dw[4]   = {0, 0, -1, 1};
        const int rhlo[4] = {1, 2, 2, 2};
        const int rhhi[4] = {33, 33, 33, 33};
        const int rwlo[4] = {3, 3, 4, 4};
        const int rwhi[4] = {36, 36, 36, 35};
        for (int d = 0; d < 4; ++d) {
            __syncthreads();
            const int nh = rhhi[d] - rhlo[d] + 1;
            const int nw = rwhi[d] - rwlo[d] + 1;
            for (int idx = tid; idx < nh * nw; idx += kThreads) {
                const int eh = rhlo[d] + idx / nw;
                const int lw = rwlo[d] + idx % nw;
                unsigned short s = prev[eh][lw];
                const unsigned short ns = prev[eh + dh[d]][lw + dw[d]];
                if ((ns & 2) && (s & 1)) {
                    const int v = (ns >> 4) & 15;
                    s = (unsigned short)((s & 0x00F0) | sVbits[v] | (v << 8) | 0x1000);
                }
                next[eh][lw] = s;
            }
            unsigned short (*t)[kLW] = prev; prev = next; next = t;
        }
    }
    __syncthreads();
    {
        const int th = tid >> 3;
        const int tw = (tid & 7) * 4;
        const int eh = th + 2;
        const size_t off = (size_t)(h0 + th) * kW + (w0 + tw);
        bool  o[4]; int src[4]; float fcaf[4]; int lb[4];
        #pragma unroll
        for (int j = 0; j < 4; ++j) {
            const unsigned short s = prev[eh][tw + 4 + j];
            o[j]    = (s & 0x1000) != 0;
            src[j]  = (s >> 8) & 15;
            fcaf[j] = (float)((s >> 4) & 15);
            lb[j]   = sPack[eh][tw + 4 + j] & 15;
        }
        #pragma unroll
        for (int c = 0; c < kNC; ++c) {
            float base[4];
            if (c >= kNE && c != kCA) {
                const float4 v = *reinterpret_cast<const float4*>(wb + (size_t)c * kPlane + off);
                base[0] = v.x; base[1] = v.y; base[2] = v.z; base[3] = v.w;
            } else if (c == kCA) {
                base[0] = fcaf[0]; base[1] = fcaf[1]; base[2] = fcaf[2]; base[3] = fcaf[3];
            } else {
                #pragma unroll
                for (int j = 0; j < 4; ++j) base[j] = (lb[j] == c) ? 1.0f : 0.0f;
            }
            float4 r;
            r.x = o[0] ? sEV[src[0] * kNC + c] : base[0];
            r.y = o[1] ? sEV[src[1] * kNC + c] : base[1];
            r.z = o[2] ? sEV[src[2] * kNC + c] : base[2];
            r.w = o[3] ? sEV[src[3] * kNC + c] : base[3];
            *reinterpret_cast<float4*>(ob + (size_t)c * kPlane + off) = r;
        }
    }
    if (blockIdx.x == 0 && blockIdx.y == 0 && blockIdx.z == 0 && tid < kB) {
        out[(size_t)kB * kNC * kPlane + tid] = info[tid];
    }
}

extern "C" void kernel_launch(void* const* d_in, const int* in_sizes, int n_in,
                              void* d_out, int out_size, void* d_ws, size_t ws_size,
                              hipStream_t stream) {
    const float* world = (const float*)d_in[0];
    const float* ev    = (const float*)d_in[1];
    const float* info  = (const float*)d_in[2];
    float* out = (float*)d_out;
    const size_t packBytes = (size_t)kB * kPlane * sizeof(unsigned short);  // 4.19 MB
    if (ws_size >= packBytes) {
        unsigned short* pack = (unsigned short*)d_ws;
        k_pack<<<dim3((kB * (int)kPlane / 4) / kThreads), kThreads, 0, stream>>>(world, info, out, pack);
        k_apply<<<dim3(kW / kT, kH / kT, kB), kThreads, 0, stream>>>(world, ev, pack, out);
    } else {
        bc_fused<<<dim3(kW / kT, kH / kT, kB), kThreads, 0, stream>>>(world, ev, info, out);
    }
}

// Round 5
// 72.139 us; speedup vs baseline: 1.9702x; 1.0048x over previous
//
#include <hip/hip_runtime.h>

namespace {
constexpr int kNE = 14;
constexpr int kNC = 20;
constexpr int kCloner = 13;
constexpr int kCA = 17;   // NE + 3
constexpr int kB = 32;
constexpr int kH = 256;
constexpr int kW = 256;

constexpr int kT = 32;        // core tile
constexpr int kE = kT + 4;    // extended rows (halo 2)
constexpr int kLW = 40;       // lds row width: [w0-4, w0+36)
constexpr int kThreads = 256;
constexpr size_t kPlane = (size_t)kH * kW;
}

// pack (uint16): bits0..3 label | bit4 cloner(label==13) | bit5 empty(label==0) | bits8..11 ca_init
// CA state (uint16): bit0 empty | bit1 active | bits4..7 fca | bits8..11 src | bit12 overwritten

// ---------------- K1: per-pixel pack, pure streaming ----------------
__global__ __launch_bounds__(kThreads)
void k_pack(const float* __restrict__ world, const float* __restrict__ info,
            float* __restrict__ out, unsigned short* __restrict__ pack)
{
    const int g = blockIdx.x * kThreads + threadIdx.x;   // 524288 float4-groups total
    const int b = g >> 14;                                // 16384 groups per plane
    const int rem = g & 16383;
    const size_t off = (size_t)rem << 2;
    const float* wb = world + (size_t)b * kNC * kPlane;

    int lab[4] = {0, 0, 0, 0};
    #pragma unroll
    for (int c = 0; c < kNE; ++c) {
        const float4 v = *reinterpret_cast<const float4*>(wb + (size_t)c * kPlane + off);
        if (v.x > 0.5f) lab[0] = c;      // exact one-hot: unique channel holds 1.0
        if (v.y > 0.5f) lab[1] = c;
        if (v.z > 0.5f) lab[2] = c;
        if (v.w > 0.5f) lab[3] = c;
    }
    const float4 ca4 = *reinterpret_cast<const float4*>(wb + (size_t)kCA * kPlane + off);
    const int cai[4] = {(int)ca4.x, (int)ca4.y, (int)ca4.z, (int)ca4.w};
    unsigned short p[4];
    #pragma unroll
    for (int j = 0; j < 4; ++j) {
        unsigned short q = (unsigned short)(lab[j] | (cai[j] << 8));
        if (lab[j] == kCloner) q |= 16;
        if (lab[j] == 0)       q |= 32;
        p[j] = q;
    }
    ushort4 st; st.x = p[0]; st.y = p[1]; st.z = p[2]; st.w = p[3];
    *reinterpret_cast<ushort4*>(pack + (size_t)b * kPlane + off) = st;

    if (g < kB) out[(size_t)kB * kNC * kPlane + g] = info[g];   // info passthrough
}

// one mask-evolution step: self s, neighbor ns (both CA-state words)
__device__ __forceinline__ unsigned bc_step(unsigned s, unsigned ns,
                                            const unsigned short* __restrict__ vb) {
    if ((ns & 2u) && (s & 1u)) {
        const unsigned v = (ns >> 4) & 15u;
        return (s & 0x00F0u) | vb[v] | (v << 8) | 0x1000u;
    }
    return s;
}

// ---------------- K2: CA evolution + output, tiled, 2 barriers ----------------
__global__ __launch_bounds__(kThreads)
void k_apply(const float* __restrict__ world, const float* __restrict__ ev,
             const unsigned short* __restrict__ pack, float* __restrict__ out)
{
    __shared__ unsigned short sPack[kE][kLW];
    __shared__ unsigned short sA[kE][kLW];
    __shared__ float sEV[kNE * kNC];
    __shared__ unsigned short sVbits[kNE];

    const int tid = threadIdx.x;
    const int b  = blockIdx.z;
    const int h0 = blockIdx.y * kT;
    const int w0 = blockIdx.x * kT;
    const float* wb = world + (size_t)b * kNC * kPlane;
    float*       ob = out   + (size_t)b * kNC * kPlane;
    const unsigned short* pb = pack + (size_t)b * kPlane;

    // Early-issue the 5 pass-through channel loads (latency hides under LDS phases).
    const int th  = tid >> 3;
    const int tw4 = (tid & 7) * 4;
    const size_t off4 = (size_t)(h0 + th) * kW + (w0 + tw4);
    float4 extra[5];
    extra[0] = *reinterpret_cast<const float4*>(wb + (size_t)14 * kPlane + off4);
    extra[1] = *reinterpret_cast<const float4*>(wb + (size_t)15 * kPlane + off4);
    extra[2] = *reinterpret_cast<const float4*>(wb + (size_t)16 * kPlane + off4);
    extra[3] = *reinterpret_cast<const float4*>(wb + (size_t)18 * kPlane + off4);
    extra[4] = *reinterpret_cast<const float4*>(wb + (size_t)19 * kPlane + off4);

    for (int i = tid; i < kNE * kNC; i += kThreads) sEV[i] = ev[i];
    if (tid < kNE) {
        const float e0  = ev[tid * kNC + 0];
        const float c13 = ev[tid * kNC + kCloner];
        const float c17 = ev[tid * kNC + kCA];
        unsigned short vb = 0;
        if (e0 > 0.5f) vb |= 1;                                     // empty after overwrite
        if (c13 > 0.5f && c17 != 0.0f && c17 != 13.0f) vb |= 2;     // active after overwrite
        sVbits[tid] = vb;
    }

    // Stage 1': packed extended tile from global (ushort4, aligned; wrap keeps 4-alignment).
    for (int idx = tid; idx < kE * 10; idx += kThreads) {
        const int eh = idx / 10;
        const int k  = idx - eh * 10;
        const int h = (h0 + eh - 2) & (kH - 1);
        const int w = (w0 - 4 + 4 * k) & (kW - 1);
        const ushort4 v = *reinterpret_cast<const ushort4*>(pb + (size_t)h * kW + w);
        sPack[eh][4 * k + 0] = v.x;
        sPack[eh][4 * k + 1] = v.y;
        sPack[eh][4 * k + 2] = v.z;
        sPack[eh][4 * k + 3] = v.w;
    }
    __syncthreads();

    // Stage 2: final CA + state init on rows 1..34, cols 3..36.
    for (int idx = tid; idx < 34 * 34; idx += kThreads) {
        const int eh = idx / 34 + 1;
        const int lw = idx % 34 + 3;
        const unsigned short p = sPack[eh][lw];
        int fca = 0;
        if (p & 16) {
            int ca = (p >> 8) & 15;
            if (ca == 0 || ca == 13) ca = sPack[eh + 1][lw] & 15;  // below
            if (ca == 0 || ca == 13) ca = sPack[eh - 1][lw] & 15;  // above
            if (ca == 0 || ca == 13) ca = sPack[eh][lw - 1] & 15;  // left
            if (ca == 0 || ca == 13) ca = sPack[eh][lw + 1] & 15;  // right
            fca = ca;
        }
        unsigned short s = (unsigned short)(fca << 4);
        if (p & 32) s |= 1;
        if ((p & 16) && fca != 0 && fca != 13) s |= 2;
        sA[eh][lw] = s;
    }
    __syncthreads();

    // Stage 3+4 fused: per-thread register simulation of the 4 direction steps
    // over the 3x6 cone of its 4 output pixels, then write all 20 channels.
    {
        const int eh  = th + 2;          // core row in ext coords (2..33)
        const int lw0 = tw4 + 4;         // first core col (4..32)

        // s0: rows eh-1..eh+1 (rel 0..2), cols lw0-1..lw0+4 (rel 0..5)
        unsigned s0[3][6];
        #pragma unroll
        for (int r = 0; r < 3; ++r)
            #pragma unroll
            for (int c = 0; c < 6; ++c)
                s0[r][c] = sA[eh - 1 + r][lw0 - 1 + c];

        // t1: dir below (neighbor row+1) — need rows rel {0,1}, all 6 cols
        unsigned s1[2][6];
        #pragma unroll
        for (int r = 0; r < 2; ++r)
            #pragma unroll
            for (int c = 0; c < 6; ++c)
                s1[r][c] = bc_step(s0[r][c], s0[r + 1][c], sVbits);

        // t2: dir above (neighbor row-1) — need row rel 1 (core), all 6 cols
        unsigned s2[6];
        #pragma unroll
        for (int c = 0; c < 6; ++c)
            s2[c] = bc_step(s1[1][c], s1[0][c], sVbits);

        // t3: dir left (neighbor col-1) — need cols rel 1..5
        unsigned s3[5];
        #pragma unroll
        for (int c = 0; c < 5; ++c)
            s3[c] = bc_step(s2[c + 1], s2[c], sVbits);

        // t4: dir right (neighbor col+1) — core cols rel 1..4 -> s3 idx 0..3 & 1..4
        unsigned s4[4];
        #pragma unroll
        for (int j = 0; j < 4; ++j)
            s4[j] = bc_step(s3[j], s3[j + 1], sVbits);

        bool  o[4]; int src[4]; float fcaf[4]; int lb[4];
        #pragma unroll
        for (int j = 0; j < 4; ++j) {
            o[j]    = (s4[j] & 0x1000u) != 0;
            src[j]  = (s4[j] >> 8) & 15;
            fcaf[j] = (float)((s4[j] >> 4) & 15);
            lb[j]   = sPack[eh][lw0 + j] & 15;
        }

        #pragma unroll
        for (int c = 0; c < kNC; ++c) {
            float base[4];
            if (c < kNE) {
                #pragma unroll
                for (int j = 0; j < 4; ++j) base[j] = (lb[j] == c) ? 1.0f : 0.0f;
            } else if (c == kCA) {
                #pragma unroll
                for (int j = 0; j < 4; ++j) base[j] = fcaf[j];
            } else {
                const float4 v = extra[c < kCA ? c - kNE : c - kNE - 1];
                base[0] = v.x; base[1] = v.y; base[2] = v.z; base[3] = v.w;
            }
            float4 r;
            r.x = o[0] ? sEV[src[0] * kNC + c] : base[0];
            r.y = o[1] ? sEV[src[1] * kNC + c] : base[1];
            r.z = o[2] ? sEV[src[2] * kNC + c] : base[2];
            r.w = o[3] ? sEV[src[3] * kNC + c] : base[3];
            *reinterpret_cast<float4*>(ob + (size_t)c * kPlane + off4) = r;
        }
    }
}

// ---------------- Fallback (proven round-3 fused kernel), used only if ws too small ----
__global__ __launch_bounds__(kThreads)
void bc_fused(const float* __restrict__ world, const float* __restrict__ ev,
              const float* __restrict__ info, float* __restrict__ out)
{
    __shared__ unsigned short sPack[kE][kLW];
    __shared__ unsigned short sA[kE][kLW];
    __shared__ unsigned short sB[kE][kLW];
    __shared__ float sEV[kNE * kNC];
    __shared__ unsigned short sVbits[kNE];

    const int tid = threadIdx.x;
    const int b  = blockIdx.z;
    const int h0 = blockIdx.y * kT;
    const int w0 = blockIdx.x * kT;
    const float* wb = world + (size_t)b * kNC * kPlane;
    float*       ob = out   + (size_t)b * kNC * kPlane;

    for (int i = tid; i < kNE * kNC; i += kThreads) sEV[i] = ev[i];
    if (tid < kNE) {
        const float e0  = ev[tid * kNC + 0];
        const float c13 = ev[tid * kNC + kCloner];
        const float c17 = ev[tid * kNC + kCA];
        unsigned short vb = 0;
        if (e0 > 0.5f) vb |= 1;
        if (c13 > 0.5f && c17 != 0.0f && c17 != 13.0f) vb |= 2;
        sVbits[tid] = vb;
    }
    for (int idx = tid; idx < kE * 10; idx += kThreads) {
        const int eh = idx / 10;
        const int k  = idx - eh * 10;
        const int h = (h0 + eh - 2) & (kH - 1);
        const int w = (w0 - 4 + 4 * k) & (kW - 1);
        const size_t off = (size_t)h * kW + w;
        int lab[4] = {0,0,0,0};
        #pragma unroll
        for (int c = 0; c < kNE; ++c) {
            const float4 v = *reinterpret_cast<const float4*>(wb + (size_t)c * kPlane + off);
            if (v.x > 0.5f) lab[0] = c;
            if (v.y > 0.5f) lab[1] = c;
            if (v.z > 0.5f) lab[2] = c;
            if (v.w > 0.5f) lab[3] = c;
        }
        const float4 ca4 = *reinterpret_cast<const float4*>(wb + (size_t)kCA * kPlane + off);
        const int cai[4] = {(int)ca4.x, (int)ca4.y, (int)ca4.z, (int)ca4.w};
        #pragma unroll
        for (int j = 0; j < 4; ++j) {
            unsigned short p = (unsigned short)(lab[j] | (cai[j] << 8));
            if (lab[j] == kCloner) p |= 16;
            if (lab[j] == 0)       p |= 32;
            sPack[eh][4 * k + j] = p;
        }
    }
    __syncthreads();
    for (int idx = tid; idx < 34 * 34; idx += kThreads) {
        const int eh = idx / 34 + 1;
        const int lw = idx % 34 + 3;
        const unsigned short p = sPack[eh][lw];
        int fca = 0;
        if (p & 16) {
            int ca = (p >> 8) & 15;
            if (ca == 0 || ca == 13) ca = sPack[eh + 1][lw] & 15;
            if (ca == 0 || ca == 13) ca = sPack[eh - 1][lw] & 15;
            if (ca == 0 || ca == 13) ca = sPack[eh][lw - 1] & 15;
            if (ca == 0 || ca == 13) ca = sPack[eh][lw + 1] & 15;
            fca = ca;
        }
        unsigned short s = (unsigned short)(fca << 4);
        if (p & 32) s |= 1;
        if ((p & 16) && fca != 0 && fca != 13) s |= 2;
        sA[eh][lw] = s;
    }
    unsigned short (*prev)[kLW] = sA;
    unsigned short (*next)[kLW] = sB;
    {
        const int dh[4]   = {1, -1, 0, 0};
        const int dw[4]   = {0, 0, -1, 1};
        const int rhlo[4] = {1, 2, 2, 2};
        const int rhhi[4] = {33, 33, 33, 33};
        const int rwlo[4] = {3, 3, 4, 4};
        const int rwhi[4] = {36, 36, 36, 35};
        for (int d = 0; d < 4; ++d) {
            __syncthreads();
            const int nh = rhhi[d] - rhlo[d] + 1;
            const int nw = rwhi[d] - rwlo[d] + 1;
            for (int idx = tid; idx < nh * nw; idx += kThreads) {
                const int eh = rhlo[d] + idx / nw;
                const int lw = rwlo[d] + idx % nw;
                unsigned short s = prev[eh][lw];
                const unsigned short ns = prev[eh + dh[d]][lw + dw[d]];
                if ((ns & 2) && (s & 1)) {
                    const int v = (ns >> 4) & 15;
                    s = (unsigned short)((s & 0x00F0) | sVbits[v] | (v << 8) | 0x1000);
                }
                next[eh][lw] = s;
            }
            unsigned short (*t)[kLW] = prev; prev = next; next = t;
        }
    }
    __syncthreads();
    {
        const int th = tid >> 3;
        const int tw = (tid & 7) * 4;
        const int eh = th + 2;
        const size_t off = (size_t)(h0 + th) * kW + (w0 + tw);
        bool  o[4]; int src[4]; float fcaf[4]; int lb[4];
        #pragma unroll
        for (int j = 0; j < 4; ++j) {
            const unsigned short s = prev[eh][tw + 4 + j];
            o[j]    = (s & 0x1000) != 0;
            src[j]  = (s >> 8) & 15;
            fcaf[j] = (float)((s >> 4) & 15);
            lb[j]   = sPack[eh][tw + 4 + j] & 15;
        }
        #pragma unroll
        for (int c = 0; c < kNC; ++c) {
            float base[4];
            if (c >= kNE && c != kCA) {
                const float4 v = *reinterpret_cast<const float4*>(wb + (size_t)c * kPlane + off);
                base[0] = v.x; base[1] = v.y; base[2] = v.z; base[3] = v.w;
            } else if (c == kCA) {
                base[0] = fcaf[0]; base[1] = fcaf[1]; base[2] = fcaf[2]; base[3] = fcaf[3];
            } else {
                #pragma unroll
                for (int j = 0; j < 4; ++j) base[j] = (lb[j] == c) ? 1.0f : 0.0f;
            }
            float4 r;
            r.x = o[0] ? sEV[src[0] * kNC + c] : base[0];
            r.y = o[1] ? sEV[src[1] * kNC + c] : base[1];
            r.z = o[2] ? sEV[src[2] * kNC + c] : base[2];
            r.w = o[3] ? sEV[src[3] * kNC + c] : base[3];
            *reinterpret_cast<float4*>(ob + (size_t)c * kPlane + off) = r;
        }
    }
    if (blockIdx.x == 0 && blockIdx.y == 0 && blockIdx.z == 0 && tid < kB) {
        out[(size_t)kB * kNC * kPlane + tid] = info[tid];
    }
}

extern "C" void kernel_launch(void* const* d_in, const int* in_sizes, int n_in,
                              void* d_out, int out_size, void* d_ws, size_t ws_size,
                              hipStream_t stream) {
    const float* world = (const float*)d_in[0];
    const float* ev    = (const float*)d_in[1];
    const float* info  = (const float*)d_in[2];
    float* out = (float*)d_out;
    const size_t packBytes = (size_t)kB * kPlane * sizeof(unsigned short);  // 4.19 MB
    if (ws_size >= packBytes) {
        unsigned short* pack = (unsigned short*)d_ws;
        k_pack<<<dim3((kB * (int)kPlane / 4) / kThreads), kThreads, 0, stream>>>(world, info, out, pack);
        k_apply<<<dim3(kW / kT, kH / kT, kB), kThreads, 0, stream>>>(world, ev, pack, out);
    } else {
        bc_fused<<<dim3(kW / kT, kH / kT, kB), kThreads, 0, stream>>>(world, ev, info, out);
    }
}